// Round 19
// baseline (586.026 us; speedup 1.0000x reference)
//
#include <hip/hip_runtime.h>

// Problem constants (match reference)
#define G_  4
#define N_  100000
#define E_  500000
#define B_  512
#define V_  50000
#define D_  300
#define H_  128
#define C_  20
#define NH_ 3

#define KP_  320   // K padded to 10 x 32 for MFMA (Wt zero-padded)
#define SCB_  512                       // elems per scan block
#define NBLK_ ((N_ + SCB_ - 1) / SCB_)  // 196

#define AROWS_  16
#define APITCH_ 320    // floats per LDS row (80 x 16B chunks)

#define GEMM_BLKS_ ((V_ + AROWS_ - 1) / AROWS_)   // 3125
#define SBLK_      ((E_ + 255) / 256)             // 1954 scatter blocks/graph

typedef unsigned short ushort_t;
typedef __attribute__((ext_vector_type(8))) short bf16x8;
typedef __attribute__((ext_vector_type(4))) float f32x4;
typedef __attribute__((ext_vector_type(4))) int   i32x4;

__device__ __forceinline__ ushort_t f2bf(float f) {
    unsigned int x = __float_as_uint(f);
    unsigned int r = x + 0x7FFFu + ((x >> 16) & 1u);   // RNE
    return (ushort_t)(r >> 16);
}

__device__ __forceinline__ int lower_bound_i(const int* __restrict__ a, int n, int v) {
    int lo = 0, hi = n;
    while (lo < hi) {
        int mid = (lo + hi) >> 1;
        if (a[mid] < v) lo = mid + 1; else hi = mid;
    }
    return lo;
}

// unpack 8 bf16 (uint4) -> 8 floats
__device__ __forceinline__ void unpack8(uint4 u, float* f) {
    f[0] = __uint_as_float((u.x & 0xFFFFu) << 16);
    f[1] = __uint_as_float(u.x & 0xFFFF0000u);
    f[2] = __uint_as_float((u.y & 0xFFFFu) << 16);
    f[3] = __uint_as_float(u.y & 0xFFFF0000u);
    f[4] = __uint_as_float((u.z & 0xFFFFu) << 16);
    f[5] = __uint_as_float(u.z & 0xFFFF0000u);
    f[6] = __uint_as_float((u.w & 0xFFFFu) << 16);
    f[7] = __uint_as_float(u.w & 0xFFFF0000u);
}

// ---------------------------------------------------------------------------
// Wt[g][n][k] = bf16(Wp[g][k][n]), k zero-padded to KP_=320. One-time, tiny.
// ---------------------------------------------------------------------------
__global__ __launch_bounds__(256) void convert_w_kernel(
    const float* __restrict__ Wp,   // [G][300][128]
    ushort_t* __restrict__ Wt)      // [G][128][KP_]
{
    int flat = blockIdx.x * 256 + threadIdx.x;   // G*128*KP_ = 163840
    int g = flat / (H_ * KP_);
    int r = flat % (H_ * KP_);
    int n = r / KP_;
    int k = r % KP_;
    float v = (k < D_) ? Wp[((size_t)g * D_ + k) * H_ + n] : 0.f;
    Wt[flat] = f2bf(v);
}

// ---------------------------------------------------------------------------
// Multi-graph MFMA GEMM, bulk-async A staging. AROWS=16 (20 KB LDS):
// 8 blocks/CU (was 4 at 40 KB) -> 32 waves/CU occupancy cap, 2x the
// independent stage/compute units in flight per CU -> staging latency hidden.
// Per block: 16 rows x 128 cols x NG graphs; 20 global_load_lds calls
// (5/wave); one vmcnt-drain barrier; 10 barrier-free K-steps.
// Bank fix (rule 21): LDS dest linear, SOURCE chunk-swizzled chunk^=(row&7),
// ds_read applies the same XOR. Pad chunks (k>=300) read finite in-row
// garbage; Wt is 0 there -> no contribution.
// ---------------------------------------------------------------------------
template <int NG>
__global__ __launch_bounds__(256) void mfma_gemm_async_kernel(
    const float* __restrict__ emb,      // [V][300] fp32
    const ushort_t* __restrict__ Wt,    // [NG][128][KP_] bf16
    const float* __restrict__ bp,       // [NG][128]
    ushort_t* __restrict__ Ph)          // [NG][V][128] bf16
{
    __shared__ float As[AROWS_ * APITCH_];   // 20 KB, flat, source-swizzled

    const int t    = threadIdx.x;
    const int w    = t >> 6;            // wave 0..3 -> col quarter
    const int l    = t & 63;
    const int l16  = l & 15;
    const int lk   = (l >> 4) * 8;      // k-octet base within K-step
    const int ch   = w * 32;
    const int rowbase = blockIdx.x * AROWS_;

    // ---- bulk async stage: 20 wave-calls x 1 KB (5 per wave) ----
#pragma unroll
    for (int j = 0; j < 5; ++j) {
        const int call      = w * 5 + j;
        const int flat_byte = call * 1024 + l * 16;   // per-lane LDS byte
        const int r         = flat_byte / 1280;       // row 0..15 (1280 B/row)
        const int q_sw      = (flat_byte - r * 1280) >> 4;   // 0..79
        int q_un = q_sw ^ (r & 7);                    // source swizzle
        int koff = q_un << 4;                         // byte offset in row
        if (koff >= 1200) koff = 0;                   // pad -> finite garbage
        int grow = rowbase + r;
        if (grow > V_ - 1) grow = V_ - 1;             // clamp (stores guarded)
        const float* gsrc = emb + (size_t)grow * D_ + (koff >> 2);
        __builtin_amdgcn_global_load_lds(
            (const __attribute__((address_space(1))) void*)gsrc,
            (__attribute__((address_space(3))) void*)(As + call * 256),
            16, 0, 0);
    }
    __syncthreads();   // drains vmcnt(0) before barrier

    f32x4 acc[NG][2];
#pragma unroll
    for (int g = 0; g < NG; ++g)
#pragma unroll
        for (int n = 0; n < 2; ++n) acc[g][n] = (f32x4){0.f, 0.f, 0.f, 0.f};

#pragma unroll
    for (int k0i = 0; k0i < 10; ++k0i) {
        const int k0 = k0i * 32;

        // A fragment: row = l16 (0..15), matched read-swizzle
        bf16x8 a;
        {
            const int r  = l16;
            const int q0 = (k0 + lk) >> 2;     // even chunk index
            const int s  = r & 7;
            float4 x0 = *reinterpret_cast<const float4*>(
                &As[r * APITCH_ + ((q0 ^ s) << 2)]);
            float4 x1 = *reinterpret_cast<const float4*>(
                &As[r * APITCH_ + (((q0 + 1) ^ s) << 2)]);
            a[0] = (short)f2bf(x0.x); a[1] = (short)f2bf(x0.y);
            a[2] = (short)f2bf(x0.z); a[3] = (short)f2bf(x0.w);
            a[4] = (short)f2bf(x1.x); a[5] = (short)f2bf(x1.y);
            a[6] = (short)f2bf(x1.z); a[7] = (short)f2bf(x1.w);
        }

        const int kb = k0 + lk;
#pragma unroll
        for (int g = 0; g < NG; ++g) {
            const ushort_t* Wg = Wt + (size_t)g * H_ * KP_;
            bf16x8 b[2];
#pragma unroll
            for (int n = 0; n < 2; ++n)
                b[n] = *reinterpret_cast<const bf16x8*>(
                    &Wg[(size_t)(ch + n * 16 + l16) * KP_ + kb]);
#pragma unroll
            for (int n = 0; n < 2; ++n)
                acc[g][n] = __builtin_amdgcn_mfma_f32_16x16x32_bf16(
                    a, b[n], acc[g][n], 0, 0, 0);
        }
    }

    // epilogue: bias + bf16 store. row = rowbase + (l>>4)*4 + r, col = ch + n*16 + l16
    const int rbase = (l >> 4) * 4;
#pragma unroll
    for (int g = 0; g < NG; ++g) {
        ushort_t* Pg = Ph + (size_t)g * V_ * H_;
#pragma unroll
        for (int n = 0; n < 2; ++n) {
            const int col  = ch + n * 16 + l16;
            const float bv = bp[g * H_ + col];
#pragma unroll
            for (int r = 0; r < 4; ++r) {
                int row = rowbase + rbase + r;
                if (row < V_)
                    Pg[(size_t)row * H_ + col] = f2bf(acc[g][n][r] + bv);
            }
        }
    }
}

// ---------------------------------------------------------------------------
// Batched CSR build over all G graphs (grid.y = g)
// ---------------------------------------------------------------------------
__global__ __launch_bounds__(256) void deg_count_kernel(const int* __restrict__ dstA,
                                                        int* __restrict__ deg)
{
    const int g = blockIdx.y;
    int e = blockIdx.x * 256 + threadIdx.x;
    if (e < E_) atomicAdd(&deg[g * N_ + dstA[(size_t)g * E_ + e]], 1);
}

__global__ __launch_bounds__(512) void scan1_kernel(const int* __restrict__ deg,
                                                    int* __restrict__ bsum)
{
    __shared__ int sh[512];
    const int g = blockIdx.y, b = blockIdx.x, t = threadIdx.x;
    int i = b * SCB_ + t;
    sh[t] = (i < N_) ? deg[g * N_ + i] : 0;
    __syncthreads();
#pragma unroll
    for (int ofs = 256; ofs > 0; ofs >>= 1) {
        if (t < ofs) sh[t] += sh[t + ofs];
        __syncthreads();
    }
    if (t == 0) bsum[g * NBLK_ + b] = sh[0];
}

__global__ __launch_bounds__(256) void scan2_kernel(const int* __restrict__ bsum,
                                                    int* __restrict__ bpre,
                                                    int* __restrict__ off)
{
    __shared__ int sh[256];
    const int g = blockIdx.x, t = threadIdx.x;
    int v = (t < NBLK_) ? bsum[g * NBLK_ + t] : 0;
    sh[t] = v;
    __syncthreads();
#pragma unroll
    for (int ofs = 1; ofs < 256; ofs <<= 1) {
        int u = (t >= ofs) ? sh[t - ofs] : 0;
        __syncthreads();
        sh[t] += u;
        __syncthreads();
    }
    if (t < NBLK_) bpre[g * (NBLK_ + 1) + t + 1] = sh[t];
    if (t == 0) {
        bpre[g * (NBLK_ + 1)] = 0;
        off[(size_t)g * (N_ + 1) + N_] = sh[NBLK_ - 1];
    }
}

__global__ __launch_bounds__(512) void scan3_kernel(int* __restrict__ deg,
                                                    const int* __restrict__ bpre,
                                                    int* __restrict__ off)
{
    __shared__ int sh[512];
    const int g = blockIdx.y, b = blockIdx.x, t = threadIdx.x;
    int i = b * SCB_ + t;
    int v = (i < N_) ? deg[g * N_ + i] : 0;
    sh[t] = v;
    __syncthreads();
#pragma unroll
    for (int ofs = 1; ofs < 512; ofs <<= 1) {
        int u = (t >= ofs) ? sh[t - ofs] : 0;
        __syncthreads();
        sh[t] += u;
        __syncthreads();
    }
    if (i < N_) {
        off[(size_t)g * (N_ + 1) + i] = bpre[g * (NBLK_ + 1) + b] + sh[t] - v;
        deg[g * N_ + i] = 0;   // becomes cnt for scatter
    }
}

// ---------------------------------------------------------------------------
// Scatter (r14 form, measured ~107us): flat grid, full occupancy, single 16B
// payload {src, vsrc, coef_bits, 0} per edge, NON-TEMPORAL store (bypasses
// per-XCD L2 write-allocate; random 16B sectors merge in memory-side L3).
// ---------------------------------------------------------------------------
__global__ __launch_bounds__(256) void scatter_kernel(
    const int* __restrict__ srcA, const int* __restrict__ dstA,
    const float* __restrict__ ewA, const float* __restrict__ ep,
    const int* __restrict__ idxA, const int* __restrict__ off,
    int* __restrict__ cnt, i32x4* __restrict__ csr4)
{
    const int g = blockIdx.y;
    int e = blockIdx.x * 256 + threadIdx.x;
    if (e >= E_) return;
    int s = srcA[(size_t)g * E_ + e];
    int d = dstA[(size_t)g * E_ + e];
    int pos = off[(size_t)g * (N_ + 1) + d] + atomicAdd(&cnt[g * N_ + d], 1);
    float w = ep[g] * ewA[(size_t)g * E_ + e];
    i32x4 v = { s, idxA[(size_t)g * N_ + s],
                __float_as_int(fmaxf(w, 0.f)), 0 };
    __builtin_nontemporal_store(v, &csr4[(size_t)g * E_ + pos]);
}

// ---------------------------------------------------------------------------
// Propagation step 1 (r13 form): 16 lanes/node x 16B, 16 nodes/block.
//   hBh[n] = bf16( P[idx[n]] + inv_deg * sum coef * P[vsrc] )
// ---------------------------------------------------------------------------
__global__ __launch_bounds__(256) void prop1_kernel(
    const int* __restrict__ idx_g, const int* __restrict__ off,
    const int4* __restrict__ csr4,
    const ushort_t* __restrict__ Ph, ushort_t* __restrict__ hBh)
{
    const int n = blockIdx.x * 16 + (threadIdx.x >> 4);
    if (n >= N_) return;
    const int lane = threadIdx.x & 15;
    const int col  = lane * 8;

    const int lo = off[n], hi = off[n + 1];

    float sf[8];
    unpack8(*reinterpret_cast<const uint4*>(&Ph[(size_t)idx_g[n] * H_ + col]), sf);

    float acc[8];
#pragma unroll
    for (int j = 0; j < 8; ++j) acc[j] = 0.f;

    int i = lo;
    for (; i + 4 <= hi; i += 4) {
        int4 e0 = csr4[i],     e1 = csr4[i + 1];
        int4 e2 = csr4[i + 2], e3 = csr4[i + 3];
        float c0 = __int_as_float(e0.z), c1 = __int_as_float(e1.z);
        float c2 = __int_as_float(e2.z), c3 = __int_as_float(e3.z);
        uint4 u0 = *reinterpret_cast<const uint4*>(&Ph[(size_t)e0.y * H_ + col]);
        uint4 u1 = *reinterpret_cast<const uint4*>(&Ph[(size_t)e1.y * H_ + col]);
        uint4 u2 = *reinterpret_cast<const uint4*>(&Ph[(size_t)e2.y * H_ + col]);
        uint4 u3 = *reinterpret_cast<const uint4*>(&Ph[(size_t)e3.y * H_ + col]);
        float f0[8], f1[8], f2[8], f3[8];
        unpack8(u0, f0); unpack8(u1, f1); unpack8(u2, f2); unpack8(u3, f3);
#pragma unroll
        for (int j = 0; j < 8; ++j)
            acc[j] += c0 * f0[j] + c1 * f1[j] + c2 * f2[j] + c3 * f3[j];
    }
    for (; i < hi; ++i) {
        int4 e0 = csr4[i];
        float c = __int_as_float(e0.z);
        float f[8];
        unpack8(*reinterpret_cast<const uint4*>(&Ph[(size_t)e0.y * H_ + col]), f);
#pragma unroll
        for (int j = 0; j < 8; ++j) acc[j] += c * f[j];
    }

    const float inv = (hi > lo) ? 1.0f / (float)(hi - lo) : 0.f;
    ushort_t p[8];
#pragma unroll
    for (int j = 0; j < 8; ++j) p[j] = f2bf(sf[j] + inv * acc[j]);
    uint4 o;
    o.x = (unsigned)p[0] | ((unsigned)p[1] << 16);
    o.y = (unsigned)p[2] | ((unsigned)p[3] << 16);
    o.z = (unsigned)p[4] | ((unsigned)p[5] << 16);
    o.w = (unsigned)p[6] | ((unsigned)p[7] << 16);
    *reinterpret_cast<uint4*>(&hBh[(size_t)n * H_ + col]) = o;
}

// ---------------------------------------------------------------------------
// Propagation step 2 + fused doc pooling (r13 form).
// ---------------------------------------------------------------------------
__global__ __launch_bounds__(256) void prop2_fused_kernel(
    const int* __restrict__ off, const int4* __restrict__ csr4,
    const int* __restrict__ gid,
    const ushort_t* __restrict__ hBh, float* __restrict__ docsum)
{
    const int nloc = threadIdx.x >> 4;          // 0..15
    const int n    = blockIdx.x * 16 + nloc;
    const int lane = threadIdx.x & 15;
    const int col  = lane * 8;

    __shared__ float sh[16][H_];
    __shared__ int   shgid[16];

    float o[8];
    if (n < N_) {
        const int lo = off[n], hi = off[n + 1];

        float sf[8];
        unpack8(*reinterpret_cast<const uint4*>(&hBh[(size_t)n * H_ + col]), sf);

        float acc[8];
#pragma unroll
        for (int j = 0; j < 8; ++j) acc[j] = 0.f;

        int i = lo;
        for (; i + 4 <= hi; i += 4) {
            int4 e0 = csr4[i],     e1 = csr4[i + 1];
            int4 e2 = csr4[i + 2], e3 = csr4[i + 3];
            float c0 = __int_as_float(e0.z), c1 = __int_as_float(e1.z);
            float c2 = __int_as_float(e2.z), c3 = __int_as_float(e3.z);
            uint4 u0 = *reinterpret_cast<const uint4*>(&hBh[(size_t)e0.x * H_ + col]);
            uint4 u1 = *reinterpret_cast<const uint4*>(&hBh[(size_t)e1.x * H_ + col]);
            uint4 u2 = *reinterpret_cast<const uint4*>(&hBh[(size_t)e2.x * H_ + col]);
            uint4 u3 = *reinterpret_cast<const uint4*>(&hBh[(size_t)e3.x * H_ + col]);
            float f0[8], f1[8], f2[8], f3[8];
            unpack8(u0, f0); unpack8(u1, f1); unpack8(u2, f2); unpack8(u3, f3);
#pragma unroll
            for (int j = 0; j < 8; ++j)
                acc[j] += c0 * f0[j] + c1 * f1[j] + c2 * f2[j] + c3 * f3[j];
        }
        for (; i < hi; ++i) {
            int4 e0 = csr4[i];
            float c = __int_as_float(e0.z);
            float f[8];
            unpack8(*reinterpret_cast<const uint4*>(&hBh[(size_t)e0.x * H_ + col]), f);
#pragma unroll
            for (int j = 0; j < 8; ++j) acc[j] += c * f[j];
        }

        const float inv = (hi > lo) ? 1.0f / (float)(hi - lo) : 0.f;
#pragma unroll
        for (int j = 0; j < 8; ++j) o[j] = sf[j] + inv * acc[j];
        if (lane == 0) shgid[nloc] = gid[n];
    } else {
#pragma unroll
        for (int j = 0; j < 8; ++j) o[j] = 0.f;
        if (lane == 0) shgid[nloc] = -1;
    }

#pragma unroll
    for (int j = 0; j < 8; ++j) sh[nloc][col + j] = o[j];
    __syncthreads();

    // run-segmented column sums: 2 halves x 128 cols; 8 nodes per half
    const int c  = threadIdx.x & 127;
    const int q  = threadIdx.x >> 7;      // 0/1
    const int n0 = q * 8;
    float run = 0.f;
    int rgid = shgid[n0];
    for (int k = 0; k < 8; ++k) {
        int gk = shgid[n0 + k];
        if (gk != rgid) {
            if (rgid >= 0) atomicAdd(&docsum[(size_t)rgid * H_ + c], run);
            run = 0.f; rgid = gk;
        }
        run += sh[n0 + k][c];
    }
    if (rgid >= 0) atomicAdd(&docsum[(size_t)rgid * H_ + c], run);
}

// ---------------------------------------------------------------------------
// Classifier from docsum: logits[g][b][:] = relu(docsum/cnt) @ Wc + bc
// ---------------------------------------------------------------------------
__global__ __launch_bounds__(128) void cls_kernel(
    const int* __restrict__ gidA, const float* __restrict__ docsum,
    const float* __restrict__ Wc, const float* __restrict__ bc,
    float* __restrict__ logits)
{
    const int b   = blockIdx.x;
    const int g   = blockIdx.y;
    const int tid = threadIdx.x;
    const int* gid = gidA + (size_t)g * N_;

    int lo = lower_bound_i(gid, N_, b);
    int hi = lower_bound_i(gid, N_, b + 1);
    float cnt = (float)(hi - lo);

    __shared__ float sdoc[H_];
    float dv = docsum[((size_t)g * B_ + b) * H_ + tid] / fmaxf(cnt, 1.0f);
    sdoc[tid] = fmaxf(dv, 0.f);
    __syncthreads();

    if (tid < C_) {
        const float* Wcg = Wc + (size_t)g * H_ * C_;
        float acc = bc[g * C_ + tid];
#pragma unroll 8
        for (int hh = 0; hh < H_; ++hh) acc += sdoc[hh] * Wcg[hh * C_ + tid];
        logits[((size_t)g * B_ + b) * C_ + tid] = acc;
    }
}

// ---------------------------------------------------------------------------
// Head fusion + mean over heads + softmax
// ---------------------------------------------------------------------------
__global__ __launch_bounds__(64) void fuse_kernel(
    const float* __restrict__ logits,  // [G][B][C]
    const float* __restrict__ Wf,      // [NH][C][C][G]
    const float* __restrict__ bf,      // [NH][C]
    float* __restrict__ out)
{
    const int b   = blockIdx.x;
    const int tid = threadIdx.x;

    __shared__ float s[C_ * G_];
    __shared__ float fl[C_];

    for (int t = tid; t < C_ * G_; t += 64) {
        int i = t >> 2, g = t & 3;
        s[t] = logits[((long)g * B_ + b) * C_ + i];
    }
    __syncthreads();

    if (tid < C_) {
        float acc = 0.f;
        for (int hd = 0; hd < NH_; ++hd) {
            float a = bf[hd * C_ + tid];
            const float* wrow = &Wf[((hd * C_ + tid) * C_) * G_];
#pragma unroll 5
            for (int i = 0; i < C_; ++i) {
#pragma unroll
                for (int g = 0; g < G_; ++g)
                    a += s[i * G_ + g] * wrow[i * G_ + g];
            }
            acc += a;
        }
        fl[tid] = acc * (1.0f / 3.0f);
    }
    __syncthreads();

    if (tid < C_) {
        float f = fl[tid];
        float m = -1e30f;
#pragma unroll
        for (int i = 0; i < C_; ++i) m = fmaxf(m, fl[i]);
        float ssum = 0.f;
#pragma unroll
        for (int i = 0; i < C_; ++i) ssum += expf(fl[i] - m);
        out[b * C_ + tid] = expf(f - m) / ssum;
        out[B_ * C_ + b * C_ + tid] = f;
    }
}

// ---------------------------------------------------------------------------
extern "C" void kernel_launch(void* const* d_in, const int* in_sizes, int n_in,
                              void* d_out, int out_size, void* d_ws, size_t ws_size,
                              hipStream_t stream)
{
    const int*   node_indices = (const int*)d_in[0];
    const int*   srcA         = (const int*)d_in[1];
    const int*   dstA         = (const int*)d_in[2];
    const int*   gidA         = (const int*)d_in[3];
    const float* ewA          = (const float*)d_in[4];
    const float* emb          = (const float*)d_in[5];
    const float* ep           = (const float*)d_in[6];
    const float* Wp           = (const float*)d_in[7];
    const float* bp           = (const float*)d_in[8];
    const float* Wc           = (const float*)d_in[9];
    const float* bc           = (const float*)d_in[10];
    const float* Wf           = (const float*)d_in[11];
    const float* bf           = (const float*)d_in[12];
    float*       out          = (float*)d_out;

    // Workspace layout (256B-aligned blocks)
    char* wp0 = (char*)d_ws;
    auto alloc = [&](size_t bytes) {
        void* r = (void*)wp0;
        wp0 += (bytes + 255) & ~(size_t)255;
        return r;
    };
    ushort_t* hBh      = (ushort_t*)alloc((size_t)N_ * H_ * 2);          // 25.6 MB
    float*    docsum   = (float*)   alloc((size_t)G_ * B_ * H_ * 4);     // 1 MB
    float*    logits   = (float*)   alloc((size_t)G_ * B_ * C_ * 4);
    ushort_t* Wt       = (ushort_t*)alloc((size_t)G_ * H_ * KP_ * 2);    // 320 KB
    int*      deg_i    = (int*)     alloc((size_t)G_ * N_ * 4);
    int*      off      = (int*)     alloc((size_t)G_ * (N_ + 1) * 4);
    int*      bsum     = (int*)     alloc((size_t)G_ * NBLK_ * 4);
    int*      bpre     = (int*)     alloc((size_t)G_ * (NBLK_ + 1) * 4);
    i32x4*    csr4     = (i32x4*)   alloc((size_t)G_ * E_ * 16);         // 32 MB

    const size_t pbytes = (size_t)V_ * H_ * 2;   // 12.8 MB per graph (bf16)
    size_t used  = (size_t)(wp0 - (char*)d_ws);
    size_t avail = (ws_size > used) ? ws_size - used : 0;

    int ng;
    if (avail >= 4 * pbytes + 1024)      ng = 4;
    else if (avail >= 2 * pbytes + 1024) ng = 2;
    else                                 ng = 1;
    ushort_t* Ph = (ushort_t*)alloc((size_t)ng * pbytes);

    // ---- one-time weight transpose+convert + zero docsum ----
    convert_w_kernel<<<(G_ * H_ * KP_) / 256, 256, 0, stream>>>(Wp, Wt);
    hipMemsetAsync(docsum, 0, (size_t)G_ * B_ * H_ * sizeof(float), stream);

    // ---- batched CSR build for all graphs ----
    hipMemsetAsync(deg_i, 0, (size_t)G_ * N_ * sizeof(int), stream);
    deg_count_kernel<<<dim3((E_ + 255) / 256, G_), 256, 0, stream>>>(dstA, deg_i);
    scan1_kernel<<<dim3(NBLK_, G_), 512, 0, stream>>>(deg_i, bsum);
    scan2_kernel<<<G_, 256, 0, stream>>>(bsum, bpre, off);
    scan3_kernel<<<dim3(NBLK_, G_), 512, 0, stream>>>(deg_i, bpre, off);
    scatter_kernel<<<dim3(SBLK_, G_), 256, 0, stream>>>(
        srcA, dstA, ewA, ep, node_indices, off, deg_i, csr4);

    // ---- per-graph-group multi-graph GEMM + per-graph propagation ----
    for (int gbase = 0; gbase < G_; gbase += ng) {
        const ushort_t* Wtg = Wt + (size_t)gbase * H_ * KP_;
        const float*    bpg = bp + (size_t)gbase * H_;
        if (ng == 4)
            mfma_gemm_async_kernel<4><<<GEMM_BLKS_, 256, 0, stream>>>(emb, Wtg, bpg, Ph);
        else if (ng == 2)
            mfma_gemm_async_kernel<2><<<GEMM_BLKS_, 256, 0, stream>>>(emb, Wtg, bpg, Ph);
        else
            mfma_gemm_async_kernel<1><<<GEMM_BLKS_, 256, 0, stream>>>(emb, Wtg, bpg, Ph);

        for (int gi = 0; gi < ng; ++gi) {
            const int g = gbase + gi;
            const int*      idx   = node_indices + (size_t)g * N_;
            const int*      gid   = gidA + (size_t)g * N_;
            const int*      off_g = off + (size_t)g * (N_ + 1);
            const int4*     csr_g = (const int4*)csr4 + (size_t)g * E_;
            const ushort_t* Pg    = Ph + (size_t)gi * V_ * H_;

            prop1_kernel<<<(N_ + 15) / 16, 256, 0, stream>>>(
                idx, off_g, csr_g, Pg, hBh);
            prop2_fused_kernel<<<(N_ + 15) / 16, 256, 0, stream>>>(
                off_g, csr_g, gid, hBh, docsum + (size_t)g * B_ * H_);
        }
    }

    cls_kernel<<<dim3(B_, G_), 128, 0, stream>>>(gidA, docsum, Wc, bc, logits);
    fuse_kernel<<<B_, 64, 0, stream>>>(logits, Wf, bf, out);
}

// Round 20
// 520.958 us; speedup vs baseline: 1.1249x; 1.1249x over previous
//
#include <hip/hip_runtime.h>

// Problem constants (match reference)
#define G_  4
#define N_  100000
#define E_  500000
#define B_  512
#define V_  50000
#define D_  300
#define H_  128
#define C_  20
#define NH_ 3

#define KP_  320   // K padded to 10 x 32 for MFMA (Wt zero-padded)
#define SCB_  512                       // elems per scan block
#define NBLK_ ((N_ + SCB_ - 1) / SCB_)  // 196

#define AROWS_  32
#define APITCH_ 320    // floats per LDS row (80 x 16B chunks)

#define SCHUNK_ 2048                    // edges per scatter chunk
#define NRANGE_ 8                       // dst ranges (one per XCD)
#define RSPAN_  (N_ / NRANGE_)          // 12500 nodes per range

typedef unsigned short ushort_t;
typedef __attribute__((ext_vector_type(8))) short bf16x8;
typedef __attribute__((ext_vector_type(4))) float f32x4;

__device__ __forceinline__ ushort_t f2bf(float f) {
    unsigned int x = __float_as_uint(f);
    unsigned int r = x + 0x7FFFu + ((x >> 16) & 1u);   // RNE
    return (ushort_t)(r >> 16);
}

__device__ __forceinline__ int lower_bound_i(const int* __restrict__ a, int n, int v) {
    int lo = 0, hi = n;
    while (lo < hi) {
        int mid = (lo + hi) >> 1;
        if (a[mid] < v) lo = mid + 1; else hi = mid;
    }
    return lo;
}

// unpack 8 bf16 (uint4) -> 8 floats
__device__ __forceinline__ void unpack8(uint4 u, float* f) {
    f[0] = __uint_as_float((u.x & 0xFFFFu) << 16);
    f[1] = __uint_as_float(u.x & 0xFFFF0000u);
    f[2] = __uint_as_float((u.y & 0xFFFFu) << 16);
    f[3] = __uint_as_float(u.y & 0xFFFF0000u);
    f[4] = __uint_as_float((u.z & 0xFFFFu) << 16);
    f[5] = __uint_as_float(u.z & 0xFFFF0000u);
    f[6] = __uint_as_float((u.w & 0xFFFFu) << 16);
    f[7] = __uint_as_float(u.w & 0xFFFF0000u);
}

// ---------------------------------------------------------------------------
// Wt[g][n][k] = bf16(Wp[g][k][n]), k zero-padded to KP_=320. One-time, tiny.
// ---------------------------------------------------------------------------
__global__ __launch_bounds__(256) void convert_w_kernel(
    const float* __restrict__ Wp,   // [G][300][128]
    ushort_t* __restrict__ Wt)      // [G][128][KP_]
{
    int flat = blockIdx.x * 256 + threadIdx.x;   // G*128*KP_ = 163840
    int g = flat / (H_ * KP_);
    int r = flat % (H_ * KP_);
    int n = r / KP_;
    int k = r % KP_;
    float v = (k < D_) ? Wp[((size_t)g * D_ + k) * H_ + n] : 0.f;
    Wt[flat] = f2bf(v);
}

// ---------------------------------------------------------------------------
// Multi-graph MFMA GEMM, bulk-async A staging (r13/r16 form, ~105us measured;
// AROWS=16 variant r19 regressed to 155us: B-traffic doubles per output row).
// ---------------------------------------------------------------------------
template <int NG>
__global__ __launch_bounds__(256) void mfma_gemm_async_kernel(
    const float* __restrict__ emb,      // [V][300] fp32
    const ushort_t* __restrict__ Wt,    // [NG][128][KP_] bf16
    const float* __restrict__ bp,       // [NG][128]
    ushort_t* __restrict__ Ph)          // [NG][V][128] bf16
{
    __shared__ float As[AROWS_ * APITCH_];   // 40 KB, flat, source-swizzled

    const int t    = threadIdx.x;
    const int w    = t >> 6;            // wave 0..3 -> col quarter
    const int l    = t & 63;
    const int l16  = l & 15;
    const int lk   = (l >> 4) * 8;      // k-octet base within K-step
    const int ch   = w * 32;
    const int rowbase = blockIdx.x * AROWS_;

    // ---- bulk async stage: 40 wave-calls x 1 KB (10 per wave) ----
#pragma unroll
    for (int j = 0; j < 10; ++j) {
        const int call      = w * 10 + j;
        const int flat_byte = call * 1024 + l * 16;   // per-lane LDS byte
        const int r         = flat_byte / 1280;       // row 0..31 (1280 B/row)
        const int q_sw      = (flat_byte - r * 1280) >> 4;   // 0..79
        int q_un = q_sw ^ (r & 7);                    // source swizzle
        int koff = q_un << 4;                         // byte offset in row
        if (koff >= 1200) koff = 0;                   // pad -> finite garbage
        int grow = rowbase + r;
        if (grow > V_ - 1) grow = V_ - 1;             // clamp (stores guarded)
        const float* gsrc = emb + (size_t)grow * D_ + (koff >> 2);
        __builtin_amdgcn_global_load_lds(
            (const __attribute__((address_space(1))) void*)gsrc,
            (__attribute__((address_space(3))) void*)(As + call * 256),
            16, 0, 0);
    }
    __syncthreads();   // drains vmcnt(0) before barrier

    f32x4 acc[NG][2][2];
#pragma unroll
    for (int g = 0; g < NG; ++g)
#pragma unroll
        for (int m = 0; m < 2; ++m)
#pragma unroll
            for (int n = 0; n < 2; ++n) acc[g][m][n] = (f32x4){0.f, 0.f, 0.f, 0.f};

#pragma unroll
    for (int k0i = 0; k0i < 10; ++k0i) {
        const int k0 = k0i * 32;

        bf16x8 a[2];
#pragma unroll
        for (int m = 0; m < 2; ++m) {
            const int r  = m * 16 + l16;
            const int q0 = (k0 + lk) >> 2;     // even chunk index
            const int s  = r & 7;
            float4 x0 = *reinterpret_cast<const float4*>(
                &As[r * APITCH_ + ((q0 ^ s) << 2)]);
            float4 x1 = *reinterpret_cast<const float4*>(
                &As[r * APITCH_ + (((q0 + 1) ^ s) << 2)]);
            a[m][0] = (short)f2bf(x0.x); a[m][1] = (short)f2bf(x0.y);
            a[m][2] = (short)f2bf(x0.z); a[m][3] = (short)f2bf(x0.w);
            a[m][4] = (short)f2bf(x1.x); a[m][5] = (short)f2bf(x1.y);
            a[m][6] = (short)f2bf(x1.z); a[m][7] = (short)f2bf(x1.w);
        }

        const int kb = k0 + lk;
#pragma unroll
        for (int g = 0; g < NG; ++g) {
            const ushort_t* Wg = Wt + (size_t)g * H_ * KP_;
            bf16x8 b[2];
#pragma unroll
            for (int n = 0; n < 2; ++n)
                b[n] = *reinterpret_cast<const bf16x8*>(
                    &Wg[(size_t)(ch + n * 16 + l16) * KP_ + kb]);
#pragma unroll
            for (int m = 0; m < 2; ++m)
#pragma unroll
                for (int n = 0; n < 2; ++n)
                    acc[g][m][n] = __builtin_amdgcn_mfma_f32_16x16x32_bf16(
                        a[m], b[n], acc[g][m][n], 0, 0, 0);
        }
    }

    // epilogue: bias + bf16 store
    const int rbase = (l >> 4) * 4;
#pragma unroll
    for (int g = 0; g < NG; ++g) {
        ushort_t* Pg = Ph + (size_t)g * V_ * H_;
#pragma unroll
        for (int n = 0; n < 2; ++n) {
            const int col  = ch + n * 16 + l16;
            const float bv = bp[g * H_ + col];
#pragma unroll
            for (int m = 0; m < 2; ++m) {
#pragma unroll
                for (int r = 0; r < 4; ++r) {
                    int row = rowbase + m * 16 + rbase + r;
                    if (row < V_)
                        Pg[(size_t)row * H_ + col] = f2bf(acc[g][m][n][r] + bv);
                }
            }
        }
    }
}

// ---------------------------------------------------------------------------
// Batched CSR build over all G graphs (grid.y = g)
// ---------------------------------------------------------------------------
__global__ __launch_bounds__(256) void deg_count_kernel(const int* __restrict__ dstA,
                                                        int* __restrict__ deg)
{
    const int g = blockIdx.y;
    int e = blockIdx.x * 256 + threadIdx.x;
    if (e < E_) atomicAdd(&deg[g * N_ + dstA[(size_t)g * E_ + e]], 1);
}

__global__ __launch_bounds__(512) void scan1_kernel(const int* __restrict__ deg,
                                                    int* __restrict__ bsum)
{
    __shared__ int sh[512];
    const int g = blockIdx.y, b = blockIdx.x, t = threadIdx.x;
    int i = b * SCB_ + t;
    sh[t] = (i < N_) ? deg[g * N_ + i] : 0;
    __syncthreads();
#pragma unroll
    for (int ofs = 256; ofs > 0; ofs >>= 1) {
        if (t < ofs) sh[t] += sh[t + ofs];
        __syncthreads();
    }
    if (t == 0) bsum[g * NBLK_ + b] = sh[0];
}

__global__ __launch_bounds__(256) void scan2_kernel(const int* __restrict__ bsum,
                                                    int* __restrict__ bpre,
                                                    int* __restrict__ off)
{
    __shared__ int sh[256];
    const int g = blockIdx.x, t = threadIdx.x;
    int v = (t < NBLK_) ? bsum[g * NBLK_ + t] : 0;
    sh[t] = v;
    __syncthreads();
#pragma unroll
    for (int ofs = 1; ofs < 256; ofs <<= 1) {
        int u = (t >= ofs) ? sh[t - ofs] : 0;
        __syncthreads();
        sh[t] += u;
        __syncthreads();
    }
    if (t < NBLK_) bpre[g * (NBLK_ + 1) + t + 1] = sh[t];
    if (t == 0) {
        bpre[g * (NBLK_ + 1)] = 0;
        off[(size_t)g * (N_ + 1) + N_] = sh[NBLK_ - 1];
    }
}

__global__ __launch_bounds__(512) void scan3_kernel(int* __restrict__ deg,
                                                    const int* __restrict__ bpre,
                                                    int* __restrict__ off)
{
    __shared__ int sh[512];
    const int g = blockIdx.y, b = blockIdx.x, t = threadIdx.x;
    int i = b * SCB_ + t;
    int v = (i < N_) ? deg[g * N_ + i] : 0;
    sh[t] = v;
    __syncthreads();
#pragma unroll
    for (int ofs = 1; ofs < 512; ofs <<= 1) {
        int u = (t >= ofs) ? sh[t - ofs] : 0;
        __syncthreads();
        sh[t] += u;
        __syncthreads();
    }
    if (i < N_) {
        off[(size_t)g * (N_ + 1) + i] = bpre[g * (NBLK_ + 1) + b] + sh[t] - v;
        deg[g * N_ + i] = 0;   // becomes cnt for scatter
    }
}

// ---------------------------------------------------------------------------
// XCD-partitioned scatter (r16 form — best measured total, 524us): blocks
// with blockIdx.x%8==r handle only dst in range r so all touches to a CSR
// line come from one XCD's L2. grid.x = NCHUNK*8.
// ---------------------------------------------------------------------------
__global__ __launch_bounds__(256) void scatter_kernel(
    const int* __restrict__ srcA, const int* __restrict__ dstA,
    const float* __restrict__ ewA, const float* __restrict__ ep,
    const int* __restrict__ idxA, const int* __restrict__ off,
    int* __restrict__ cnt, int4* __restrict__ csr4)
{
    const int g     = blockIdx.y;
    const int r     = blockIdx.x & (NRANGE_ - 1);
    const int chunk = blockIdx.x >> 3;
    const int e0    = chunk * SCHUNK_;
    const int dlo   = r * RSPAN_;
    const int dhi   = dlo + RSPAN_;
    const float epg = ep[g];

#pragma unroll
    for (int j = 0; j < SCHUNK_ / 256; ++j) {
        int e = e0 + j * 256 + threadIdx.x;
        if (e >= E_) continue;
        int d = dstA[(size_t)g * E_ + e];
        if (d < dlo || d >= dhi) continue;
        int s = srcA[(size_t)g * E_ + e];
        int pos = off[(size_t)g * (N_ + 1) + d] + atomicAdd(&cnt[g * N_ + d], 1);
        float w = epg * ewA[(size_t)g * E_ + e];
        csr4[(size_t)g * E_ + pos] =
            make_int4(s, idxA[(size_t)g * N_ + s], __float_as_int(fmaxf(w, 0.f)), 0);
    }
}

// ---------------------------------------------------------------------------
// Propagation step 1 (r13 form): 16 lanes/node x 16B, 16 nodes/block.
//   hBh[n] = bf16( P[idx[n]] + inv_deg * sum coef * P[vsrc] )
// ---------------------------------------------------------------------------
__global__ __launch_bounds__(256) void prop1_kernel(
    const int* __restrict__ idx_g, const int* __restrict__ off,
    const int4* __restrict__ csr4,
    const ushort_t* __restrict__ Ph, ushort_t* __restrict__ hBh)
{
    const int n = blockIdx.x * 16 + (threadIdx.x >> 4);
    if (n >= N_) return;
    const int lane = threadIdx.x & 15;
    const int col  = lane * 8;

    const int lo = off[n], hi = off[n + 1];

    float sf[8];
    unpack8(*reinterpret_cast<const uint4*>(&Ph[(size_t)idx_g[n] * H_ + col]), sf);

    float acc[8];
#pragma unroll
    for (int j = 0; j < 8; ++j) acc[j] = 0.f;

    int i = lo;
    for (; i + 4 <= hi; i += 4) {
        int4 e0 = csr4[i],     e1 = csr4[i + 1];
        int4 e2 = csr4[i + 2], e3 = csr4[i + 3];
        float c0 = __int_as_float(e0.z), c1 = __int_as_float(e1.z);
        float c2 = __int_as_float(e2.z), c3 = __int_as_float(e3.z);
        uint4 u0 = *reinterpret_cast<const uint4*>(&Ph[(size_t)e0.y * H_ + col]);
        uint4 u1 = *reinterpret_cast<const uint4*>(&Ph[(size_t)e1.y * H_ + col]);
        uint4 u2 = *reinterpret_cast<const uint4*>(&Ph[(size_t)e2.y * H_ + col]);
        uint4 u3 = *reinterpret_cast<const uint4*>(&Ph[(size_t)e3.y * H_ + col]);
        float f0[8], f1[8], f2[8], f3[8];
        unpack8(u0, f0); unpack8(u1, f1); unpack8(u2, f2); unpack8(u3, f3);
#pragma unroll
        for (int j = 0; j < 8; ++j)
            acc[j] += c0 * f0[j] + c1 * f1[j] + c2 * f2[j] + c3 * f3[j];
    }
    for (; i < hi; ++i) {
        int4 e0 = csr4[i];
        float c = __int_as_float(e0.z);
        float f[8];
        unpack8(*reinterpret_cast<const uint4*>(&Ph[(size_t)e0.y * H_ + col]), f);
#pragma unroll
        for (int j = 0; j < 8; ++j) acc[j] += c * f[j];
    }

    const float inv = (hi > lo) ? 1.0f / (float)(hi - lo) : 0.f;
    ushort_t p[8];
#pragma unroll
    for (int j = 0; j < 8; ++j) p[j] = f2bf(sf[j] + inv * acc[j]);
    uint4 o;
    o.x = (unsigned)p[0] | ((unsigned)p[1] << 16);
    o.y = (unsigned)p[2] | ((unsigned)p[3] << 16);
    o.z = (unsigned)p[4] | ((unsigned)p[5] << 16);
    o.w = (unsigned)p[6] | ((unsigned)p[7] << 16);
    *reinterpret_cast<uint4*>(&hBh[(size_t)n * H_ + col]) = o;
}

// ---------------------------------------------------------------------------
// Propagation step 2 + fused doc pooling (r13 form).
// ---------------------------------------------------------------------------
__global__ __launch_bounds__(256) void prop2_fused_kernel(
    const int* __restrict__ off, const int4* __restrict__ csr4,
    const int* __restrict__ gid,
    const ushort_t* __restrict__ hBh, float* __restrict__ docsum)
{
    const int nloc = threadIdx.x >> 4;          // 0..15
    const int n    = blockIdx.x * 16 + nloc;
    const int lane = threadIdx.x & 15;
    const int col  = lane * 8;

    __shared__ float sh[16][H_];
    __shared__ int   shgid[16];

    float o[8];
    if (n < N_) {
        const int lo = off[n], hi = off[n + 1];

        float sf[8];
        unpack8(*reinterpret_cast<const uint4*>(&hBh[(size_t)n * H_ + col]), sf);

        float acc[8];
#pragma unroll
        for (int j = 0; j < 8; ++j) acc[j] = 0.f;

        int i = lo;
        for (; i + 4 <= hi; i += 4) {
            int4 e0 = csr4[i],     e1 = csr4[i + 1];
            int4 e2 = csr4[i + 2], e3 = csr4[i + 3];
            float c0 = __int_as_float(e0.z), c1 = __int_as_float(e1.z);
            float c2 = __int_as_float(e2.z), c3 = __int_as_float(e3.z);
            uint4 u0 = *reinterpret_cast<const uint4*>(&hBh[(size_t)e0.x * H_ + col]);
            uint4 u1 = *reinterpret_cast<const uint4*>(&hBh[(size_t)e1.x * H_ + col]);
            uint4 u2 = *reinterpret_cast<const uint4*>(&hBh[(size_t)e2.x * H_ + col]);
            uint4 u3 = *reinterpret_cast<const uint4*>(&hBh[(size_t)e3.x * H_ + col]);
            float f0[8], f1[8], f2[8], f3[8];
            unpack8(u0, f0); unpack8(u1, f1); unpack8(u2, f2); unpack8(u3, f3);
#pragma unroll
            for (int j = 0; j < 8; ++j)
                acc[j] += c0 * f0[j] + c1 * f1[j] + c2 * f2[j] + c3 * f3[j];
        }
        for (; i < hi; ++i) {
            int4 e0 = csr4[i];
            float c = __int_as_float(e0.z);
            float f[8];
            unpack8(*reinterpret_cast<const uint4*>(&hBh[(size_t)e0.x * H_ + col]), f);
#pragma unroll
            for (int j = 0; j < 8; ++j) acc[j] += c * f[j];
        }

        const float inv = (hi > lo) ? 1.0f / (float)(hi - lo) : 0.f;
#pragma unroll
        for (int j = 0; j < 8; ++j) o[j] = sf[j] + inv * acc[j];
        if (lane == 0) shgid[nloc] = gid[n];
    } else {
#pragma unroll
        for (int j = 0; j < 8; ++j) o[j] = 0.f;
        if (lane == 0) shgid[nloc] = -1;
    }

#pragma unroll
    for (int j = 0; j < 8; ++j) sh[nloc][col + j] = o[j];
    __syncthreads();

    // run-segmented column sums: 2 halves x 128 cols; 8 nodes per half
    const int c  = threadIdx.x & 127;
    const int q  = threadIdx.x >> 7;      // 0/1
    const int n0 = q * 8;
    float run = 0.f;
    int rgid = shgid[n0];
    for (int k = 0; k < 8; ++k) {
        int gk = shgid[n0 + k];
        if (gk != rgid) {
            if (rgid >= 0) atomicAdd(&docsum[(size_t)rgid * H_ + c], run);
            run = 0.f; rgid = gk;
        }
        run += sh[n0 + k][c];
    }
    if (rgid >= 0) atomicAdd(&docsum[(size_t)rgid * H_ + c], run);
}

// ---------------------------------------------------------------------------
// Classifier from docsum: logits[g][b][:] = relu(docsum/cnt) @ Wc + bc
// ---------------------------------------------------------------------------
__global__ __launch_bounds__(128) void cls_kernel(
    const int* __restrict__ gidA, const float* __restrict__ docsum,
    const float* __restrict__ Wc, const float* __restrict__ bc,
    float* __restrict__ logits)
{
    const int b   = blockIdx.x;
    const int g   = blockIdx.y;
    const int tid = threadIdx.x;
    const int* gid = gidA + (size_t)g * N_;

    int lo = lower_bound_i(gid, N_, b);
    int hi = lower_bound_i(gid, N_, b + 1);
    float cnt = (float)(hi - lo);

    __shared__ float sdoc[H_];
    float dv = docsum[((size_t)g * B_ + b) * H_ + tid] / fmaxf(cnt, 1.0f);
    sdoc[tid] = fmaxf(dv, 0.f);
    __syncthreads();

    if (tid < C_) {
        const float* Wcg = Wc + (size_t)g * H_ * C_;
        float acc = bc[g * C_ + tid];
#pragma unroll 8
        for (int hh = 0; hh < H_; ++hh) acc += sdoc[hh] * Wcg[hh * C_ + tid];
        logits[((size_t)g * B_ + b) * C_ + tid] = acc;
    }
}

// ---------------------------------------------------------------------------
// Head fusion + mean over heads + softmax
// ---------------------------------------------------------------------------
__global__ __launch_bounds__(64) void fuse_kernel(
    const float* __restrict__ logits,  // [G][B][C]
    const float* __restrict__ Wf,      // [NH][C][C][G]
    const float* __restrict__ bf,      // [NH][C]
    float* __restrict__ out)
{
    const int b   = blockIdx.x;
    const int tid = threadIdx.x;

    __shared__ float s[C_ * G_];
    __shared__ float fl[C_];

    for (int t = tid; t < C_ * G_; t += 64) {
        int i = t >> 2, g = t & 3;
        s[t] = logits[((long)g * B_ + b) * C_ + i];
    }
    __syncthreads();

    if (tid < C_) {
        float acc = 0.f;
        for (int hd = 0; hd < NH_; ++hd) {
            float a = bf[hd * C_ + tid];
            const float* wrow = &Wf[((hd * C_ + tid) * C_) * G_];
#pragma unroll 5
            for (int i = 0; i < C_; ++i) {
#pragma unroll
                for (int g = 0; g < G_; ++g)
                    a += s[i * G_ + g] * wrow[i * G_ + g];
            }
            acc += a;
        }
        fl[tid] = acc * (1.0f / 3.0f);
    }
    __syncthreads();

    if (tid < C_) {
        float f = fl[tid];
        float m = -1e30f;
#pragma unroll
        for (int i = 0; i < C_; ++i) m = fmaxf(m, fl[i]);
        float ssum = 0.f;
#pragma unroll
        for (int i = 0; i < C_; ++i) ssum += expf(fl[i] - m);
        out[b * C_ + tid] = expf(f - m) / ssum;
        out[B_ * C_ + b * C_ + tid] = f;
    }
}

// ---------------------------------------------------------------------------
extern "C" void kernel_launch(void* const* d_in, const int* in_sizes, int n_in,
                              void* d_out, int out_size, void* d_ws, size_t ws_size,
                              hipStream_t stream)
{
    const int*   node_indices = (const int*)d_in[0];
    const int*   srcA         = (const int*)d_in[1];
    const int*   dstA         = (const int*)d_in[2];
    const int*   gidA         = (const int*)d_in[3];
    const float* ewA          = (const float*)d_in[4];
    const float* emb          = (const float*)d_in[5];
    const float* ep           = (const float*)d_in[6];
    const float* Wp           = (const float*)d_in[7];
    const float* bp           = (const float*)d_in[8];
    const float* Wc           = (const float*)d_in[9];
    const float* bc           = (const float*)d_in[10];
    const float* Wf           = (const float*)d_in[11];
    const float* bf           = (const float*)d_in[12];
    float*       out          = (float*)d_out;

    // Workspace layout (256B-aligned blocks)
    char* wp0 = (char*)d_ws;
    auto alloc = [&](size_t bytes) {
        void* r = (void*)wp0;
        wp0 += (bytes + 255) & ~(size_t)255;
        return r;
    };
    ushort_t* hBh      = (ushort_t*)alloc((size_t)N_ * H_ * 2);          // 25.6 MB
    float*    docsum   = (float*)   alloc((size_t)G_ * B_ * H_ * 4);     // 1 MB
    float*    logits   = (float*)   alloc((size_t)G_ * B_ * C_ * 4);
    ushort_t* Wt       = (ushort_t*)alloc((size_t)G_ * H_ * KP_ * 2);    // 320 KB
    int*      deg_i    = (int*)     alloc((size_t)G_ * N_ * 4);
    int*      off      = (int*)     alloc((size_t)G_ * (N_ + 1) * 4);
    int*      bsum     = (int*)     alloc((size_t)G_ * NBLK_ * 4);
    int*      bpre     = (int*)     alloc((size_t)G_ * (NBLK_ + 1) * 4);
    int4*     csr4     = (int4*)    alloc((size_t)G_ * E_ * 16);         // 32 MB

    const size_t pbytes = (size_t)V_ * H_ * 2;   // 12.8 MB per graph (bf16)
    size_t used  = (size_t)(wp0 - (char*)d_ws);
    size_t avail = (ws_size > used) ? ws_size - used : 0;

    int ng;
    if (avail >= 4 * pbytes + 1024)      ng = 4;
    else if (avail >= 2 * pbytes + 1024) ng = 2;
    else                                 ng = 1;
    ushort_t* Ph = (ushort_t*)alloc((size_t)ng * pbytes);

    // ---- one-time weight transpose+convert + zero docsum ----
    convert_w_kernel<<<(G_ * H_ * KP_) / 256, 256, 0, stream>>>(Wp, Wt);
    hipMemsetAsync(docsum, 0, (size_t)G_ * B_ * H_ * sizeof(float), stream);

    // ---- batched CSR build for all graphs ----
    hipMemsetAsync(deg_i, 0, (size_t)G_ * N_ * sizeof(int), stream);
    deg_count_kernel<<<dim3((E_ + 255) / 256, G_), 256, 0, stream>>>(dstA, deg_i);
    scan1_kernel<<<dim3(NBLK_, G_), 512, 0, stream>>>(deg_i, bsum);
    scan2_kernel<<<G_, 256, 0, stream>>>(bsum, bpre, off);
    scan3_kernel<<<dim3(NBLK_, G_), 512, 0, stream>>>(deg_i, bpre, off);
    const int nchunk = (E_ + SCHUNK_ - 1) / SCHUNK_;
    scatter_kernel<<<dim3(nchunk * NRANGE_, G_), 256, 0, stream>>>(
        srcA, dstA, ewA, ep, node_indices, off, deg_i, csr4);

    // ---- per-graph-group multi-graph GEMM + per-graph propagation ----
    const int gemm_blocks = (V_ + AROWS_ - 1) / AROWS_;
    for (int gbase = 0; gbase < G_; gbase += ng) {
        const ushort_t* Wtg = Wt + (size_t)gbase * H_ * KP_;
        const float*    bpg = bp + (size_t)gbase * H_;
        if (ng == 4)
            mfma_gemm_async_kernel<4><<<gemm_blocks, 256, 0, stream>>>(emb, Wtg, bpg, Ph);
        else if (ng == 2)
            mfma_gemm_async_kernel<2><<<gemm_blocks, 256, 0, stream>>>(emb, Wtg, bpg, Ph);
        else
            mfma_gemm_async_kernel<1><<<gemm_blocks, 256, 0, stream>>>(emb, Wtg, bpg, Ph);

        for (int gi = 0; gi < ng; ++gi) {
            const int g = gbase + gi;
            const int*      idx   = node_indices + (size_t)g * N_;
            const int*      gid   = gidA + (size_t)g * N_;
            const int*      off_g = off + (size_t)g * (N_ + 1);
            const int4*     csr_g = (const int4*)csr4 + (size_t)g * E_;
            const ushort_t* Pg    = Ph + (size_t)gi * V_ * H_;

            prop1_kernel<<<(N_ + 15) / 16, 256, 0, stream>>>(
                idx, off_g, csr_g, Pg, hBh);
            prop2_fused_kernel<<<(N_ + 15) / 16, 256, 0, stream>>>(
                off_g, csr_g, gid, hBh, docsum + (size_t)g * B_ * H_);
        }
    }

    cls_kernel<<<dim3(B_, G_), 128, 0, stream>>>(gidA, docsum, Wc, bc, logits);
    fuse_kernel<<<B_, 64, 0, stream>>>(logits, Wf, bf, out);
}